// Round 3
// baseline (69.936 us; speedup 1.0000x reference)
//
#include <hip/hip_runtime.h>

#define NROWS  50000
#define NF     32
#define NTREES 300
#define NINT   63
#define NLEAF  64
#define LRATE  0.1f
#define RPB    256     // rows per block == threads per block
#define TPG    30      // trees per group (multiple of 6 for ILP-6, and of 3 classes)
#define TG     10      // tree groups (grid.y); TPG*TG == NTREES

__global__ void gb_init_out(const float* __restrict__ initp,
                            float* __restrict__ out, int n) {
    int i = blockIdx.x * blockDim.x + threadIdx.x;
    if (i < n) out[i] = initp[i % 3];
}

// pack {feat, thr} -> int2 table [NTREES][64] in workspace (64 for alignment)
__global__ void gb_pack(const int* __restrict__ feat, const float* __restrict__ thr,
                        int2* __restrict__ pack) {
    int i = blockIdx.x * blockDim.x + threadIdx.x;
    if (i >= NTREES * 64) return;
    int t = i >> 6, n = i & 63;
    int2 v = make_int2(0, 0);
    if (n < NINT) {
        v.x = feat[t * NINT + n];
        v.y = __float_as_int(thr[t * NINT + n]);
    }
    pack[i] = v;
}

// PACKED=1: nodes come from the int2 table in d_ws (1 VMEM load/level)
// PACKED=0: fallback, nodes read from feat/thr directly (2 VMEM loads/level)
template <bool PACKED>
__global__ __launch_bounds__(RPB, 5) void gb_forest(
    const float* __restrict__ x,      // [NROWS][NF]
    const int*   __restrict__ feat,   // [NTREES][NINT]
    const float* __restrict__ thr,    // [NTREES][NINT]
    const int2*  __restrict__ pack,   // [NTREES][64] packed nodes (ws)
    const float* __restrict__ leaves, // [NTREES][NLEAF]
    float*       __restrict__ out)    // [NROWS][3]
{
    __shared__ float xs[NF][RPB];     // 32 KB only -> 5 blocks/CU (160 KB)

    const int tid  = threadIdx.x;
    const int r0   = blockIdx.x * RPB;
    const int m0   = blockIdx.y * TPG;
    const int grow = r0 + tid;

    // stage x: each thread loads its own row (8x float4), writes transposed
    // -> LDS write bank = tid%32, conflict-free; reads xs[f][tid] conflict-free
    {
        const float4* xr = (const float4*)x +
            (size_t)(grow < NROWS ? grow : NROWS - 1) * (NF / 4);
        float4 v[8];
        #pragma unroll
        for (int k = 0; k < 8; ++k) v[k] = xr[k];
        #pragma unroll
        for (int k = 0; k < 8; ++k) {
            xs[k * 4 + 0][tid] = v[k].x;
            xs[k * 4 + 1][tid] = v[k].y;
            xs[k * 4 + 2][tid] = v[k].z;
            xs[k * 4 + 3][tid] = v[k].w;
        }
    }
    __syncthreads();

    float acc0 = 0.f, acc1 = 0.f, acc2 = 0.f;
    for (int it = 0; it < TPG; it += 6) {
        int idx[6] = {0, 0, 0, 0, 0, 0};   // unrolled loops only -> stays in regs
        #pragma unroll
        for (int d = 0; d < 6; ++d) {
            #pragma unroll
            for (int j = 0; j < 6; ++j) {
                int f; float t;
                if (PACKED) {
                    int2 nd = pack[(size_t)(m0 + it + j) * 64 + idx[j]];
                    f = nd.x; t = __int_as_float(nd.y);
                } else {
                    f = feat[(m0 + it + j) * NINT + idx[j]];
                    t = thr [(m0 + it + j) * NINT + idx[j]];
                }
                // sklearn: left (+1) iff x <= t, right (+2) otherwise
                idx[j] = 2 * idx[j] + 1 + (int)(xs[f][tid] > t);
            }
        }
        #pragma unroll
        for (int j = 0; j < 6; ++j) {
            float lv = leaves[(m0 + it + j) * NLEAF + (idx[j] - NINT)];
            if (j % 3 == 0)      acc0 += lv;
            else if (j % 3 == 1) acc1 += lv;
            else                 acc2 += lv;
        }
    }

    if (grow < NROWS) {
        atomicAdd(&out[grow * 3 + 0], LRATE * acc0);
        atomicAdd(&out[grow * 3 + 1], LRATE * acc1);
        atomicAdd(&out[grow * 3 + 2], LRATE * acc2);
    }
}

extern "C" void kernel_launch(void* const* d_in, const int* in_sizes, int n_in,
                              void* d_out, int out_size, void* d_ws, size_t ws_size,
                              hipStream_t stream) {
    const float* x      = (const float*)d_in[0];
    const int*   feat   = (const int*)d_in[1];
    const float* thr    = (const float*)d_in[2];
    const float* leaves = (const float*)d_in[3];
    const float* initp  = (const float*)d_in[4];
    float* out = (float*)d_out;

    gb_init_out<<<(out_size + 255) / 256, 256, 0, stream>>>(initp, out, out_size);

    dim3 grid((NROWS + RPB - 1) / RPB, TG);
    const size_t pack_bytes = (size_t)NTREES * 64 * sizeof(int2);
    if (ws_size >= pack_bytes) {
        int2* pack = (int2*)d_ws;
        gb_pack<<<(NTREES * 64 + 255) / 256, 256, 0, stream>>>(feat, thr, pack);
        gb_forest<true><<<grid, RPB, 0, stream>>>(x, feat, thr, pack, leaves, out);
    } else {
        gb_forest<false><<<grid, RPB, 0, stream>>>(x, feat, thr, nullptr, leaves, out);
    }
}